// Round 12
// baseline (163.917 us; speedup 1.0000x reference)
//
#include <hip/hip_runtime.h>
#include <hip/hip_bf16.h>

#define DIMC 256
#define NB 4
#define NS 4096
#define KT 32               // keys per phase in attention

typedef __attribute__((ext_vector_type(4))) float f32x4;
typedef __attribute__((ext_vector_type(8))) short bf16x8;

__device__ __forceinline__ ushort f2bf(float f) {
  __hip_bfloat16 h = __float2bfloat16(f);
  return *reinterpret_cast<ushort*>(&h);
}
__device__ __forceinline__ float bf2f(ushort h) {
  uint u = ((uint)h) << 16;
  float f;
  __builtin_memcpy(&f, &u, 4);
  return f;
}

// async global->LDS DMA, 16B per lane; LDS dest = wave-uniform base + lane*16
__device__ __forceinline__ void gload16(const ushort* g, ushort* l) {
  __builtin_amdgcn_global_load_lds(
      (const __attribute__((address_space(1))) unsigned int*)g,
      (__attribute__((address_space(3))) unsigned int*)l,
      16, 0, 0);
}

// ---------------- prep: W hi/lo split + mask pack (one launch) ----------------
__global__ __launch_bounds__(256) void prep_kernel(
    const float* __restrict__ W, const int* __restrict__ mask,
    ushort* __restrict__ Whl, uint* __restrict__ pm32)
{
  if (blockIdx.x < 512) {
    const int col = blockIdx.x;          // 0..511
    const int k = threadIdx.x;           // 0..255
    const int srcrow = (col < 256) ? col : (col + 256);
    float f = W[(size_t)srcrow * 256 + k];
    ushort h = f2bf(f);
    Whl[(size_t)col * 256 + k] = h;
    Whl[131072 + (size_t)col * 256 + k] = f2bf(f - bf2f(h));
  } else {
    int t = (blockIdx.x - 512) * 256 + threadIdx.x;   // 0..511
    int b = t >> 7;
    int kt = (t >> 1) & 63;
    int kh = t & 1;
    const int* mrow = mask + b * NS + kt * 64 + kh * 32;
    uint wd = 0;
    for (int g = 0; g < 4; ++g)
      for (int ntl = 0; ntl < 2; ++ntl)
        for (int r = 0; r < 4; ++r)
          if (mrow[ntl * 16 + 4 * g + r] != 0) wd |= 1u << (8 * g + ntl * 4 + r);
    pm32[t] = wd;
  }
}

// ---------------- QV projection via MFMA (3-term bf16 compensation) ----------
// R8-validated 64-row version (grid 256).
__global__ __launch_bounds__(256) void qv_proj_kernel(
    const float* __restrict__ x, const ushort* __restrict__ Whl,
    const float* __restrict__ bias,
    ushort* __restrict__ qb, ushort* __restrict__ vb, ushort* __restrict__ vtb)
{
  const int tid  = threadIdx.x;
  const int w    = tid >> 6;
  const int lane = tid & 63;
  const int l15  = lane & 15;
  const int g    = (lane >> 4) & 3;
  const int r0   = blockIdx.x << 6;    // 64 rows
  const int colbase = w << 7;          // 128 cols per wave

  __shared__ ushort olds[64 * 520];    // output transpose staging (65KB)

  f32x4 acc[4][8];
  #pragma unroll
  for (int rt = 0; rt < 4; ++rt)
    #pragma unroll
    for (int ct = 0; ct < 8; ++ct) { acc[rt][ct].x=0.f; acc[rt][ct].y=0.f; acc[rt][ct].z=0.f; acc[rt][ct].w=0.f; }

  #pragma unroll 1
  for (int st = 0; st < 8; ++st) {
    bf16x8 xh[4], xl[4];
    #pragma unroll
    for (int rt = 0; rt < 4; ++rt) {
      const float* p = x + (size_t)(r0 + rt * 16 + l15) * DIMC + st * 32 + g * 8;
      float4 f0 = *(const float4*)p;
      float4 f1 = *(const float4*)(p + 4);
      union { bf16x8 v; ushort u[8]; } uh, ul;
      #pragma unroll
      for (int e = 0; e < 8; ++e) {
        float fe = (e < 4) ? ((const float*)&f0)[e] : ((const float*)&f1)[e - 4];
        ushort h = f2bf(fe);
        uh.u[e] = h;
        ul.u[e] = f2bf(fe - bf2f(h));
      }
      xh[rt] = uh.v;
      xl[rt] = ul.v;
    }
    #pragma unroll
    for (int ct = 0; ct < 8; ++ct) {
      const ushort* wp = Whl + (size_t)(colbase + ct * 16 + l15) * 256 + st * 32 + g * 8;
      bf16x8 wh = *(const bf16x8*)wp;
      bf16x8 wl = *(const bf16x8*)(wp + 131072);
      #pragma unroll
      for (int rt = 0; rt < 4; ++rt) {
        acc[rt][ct] = __builtin_amdgcn_mfma_f32_16x16x32_bf16(xh[rt], wh, acc[rt][ct], 0, 0, 0);
        acc[rt][ct] = __builtin_amdgcn_mfma_f32_16x16x32_bf16(xl[rt], wh, acc[rt][ct], 0, 0, 0);
        acc[rt][ct] = __builtin_amdgcn_mfma_f32_16x16x32_bf16(xh[rt], wl, acc[rt][ct], 0, 0, 0);
      }
    }
  }

  const float qscale = (colbase < 256) ? 0.0625f : 1.0f;
  #pragma unroll
  for (int ct = 0; ct < 8; ++ct) {
    const int col = colbase + ct * 16 + l15;
    const float bv = bias[(col < 256) ? col : (col + 256)];
    #pragma unroll
    for (int rt = 0; rt < 4; ++rt) {
      #pragma unroll
      for (int r = 0; r < 4; ++r)
        olds[(rt * 16 + 4 * g + r) * 520 + col] = f2bf((acc[rt][ct][r] + bv) * qscale);
    }
  }
  __syncthreads();

  #pragma unroll
  for (int i = 0; i < 16; ++i) {
    int task = tid + i * 256;
    int row = task >> 6, ch = task & 63;
    uint4 d = *(const uint4*)&olds[row * 520 + ch * 8];
    if (ch < 32) *(uint4*)&qb[(size_t)(r0 + row) * DIMC + ch * 8] = d;
    else         *(uint4*)&vb[(size_t)(r0 + row) * DIMC + (ch - 32) * 8] = d;
  }
  const int bbp = r0 >> 12;
  const int s0  = r0 & (NS - 1);
  const int vcol = tid;
  #pragma unroll
  for (int o = 0; o < 8; ++o) {
    union { uint4 v; ushort u[8]; } pk;
    #pragma unroll
    for (int j = 0; j < 8; ++j)
      pk.u[j] = olds[(o * 8 + j) * 520 + 256 + vcol];
    *(uint4*)&vtb[((size_t)(bbp * DIMC + vcol)) * NS + s0 + o * 8] = pk.v;
  }
}

// ---------------- flash attention: qt=1, KT=32, 16 waves/CU ------------------
// Grid 512 = 256 q-blocks (64 rows) x 2 split-K halves (2048 keys, 64 phases).
// Block: 512 threads = 8 waves = 4 pq (16 q rows) x 2 kh.
// kh: QK^T computes S^T for its 16-key half; PV computes its 128-d half over
// the full 32 keys (lagged one phase, ps exchange in LDS). 70KB LDS ->
// 2 blocks/CU; VGPR capped 128 via __launch_bounds__(512,4) -> 4 waves/SIMD.
__global__ __launch_bounds__(512, 4) void attn_kernel(
    const ushort* __restrict__ qb, const ushort* __restrict__ vb,
    const ushort* __restrict__ vtb, const uint* __restrict__ pm32,
    float* __restrict__ outA, float* __restrict__ opB,
    float* __restrict__ mlA, float* __restrict__ mlB)
{
  const int tid  = threadIdx.x;
  const int w    = tid >> 6;      // 0..7
  const int lane = tid & 63;
  const int l15  = lane & 15;
  const int g    = (lane >> 4) & 3;
  const int kh   = w & 1;         // key half (QK^T) / d half (PV)
  const int pq   = w >> 1;        // 16-row q-subrange (0..3)

  const int s     = blockIdx.x & 1;          // split-K half
  const int qb64  = blockIdx.x >> 1;
  const int qrow0 = qb64 << 6;               // 64 q rows per block
  const int bb    = qrow0 >> 12;
  const int koff  = s << 11;                 // 2048-key offset

  float* opart = s ? opB : outA;
  float* mlp   = s ? mlB : mlA;

  extern __shared__ __align__(16) char smem[];
  uint*   pmlds = (uint*)smem;                        // 512 B (pad 1KB)
  ushort* vs0  = (ushort*)(smem + 1024);              // 16KB key-major V (swizzled)
  ushort* vs1  = vs0 + KT * DIMC;
  ushort* vt0  = vs1 + KT * DIMC;                     // 16KB V^T 8-key chunks
  ushort* vt1  = vt0 + KT * DIMC;
  ushort* psb  = vt1 + KT * DIMC;                     // 4 pq x 16 q x 40 = 5KB

  // ---- Q into registers (16 rows per wave)
  const int qrow_w = qrow0 + (pq << 4) + l15;
  bf16x8 qreg[8];
  #pragma unroll
  for (int st = 0; st < 8; ++st)
    qreg[st] = *(const bf16x8*)&qb[(size_t)qrow_w * DIMC + ((st * 4 + g) << 3)];

  if (tid < 128) pmlds[tid] = pm32[(bb << 7) + tid];

  auto stage_vs = [&](int kt, ushort* vsN) {
    const ushort* vbase = vb + ((size_t)(bb * NS + koff + kt * KT)) * DIMC;
    #pragma unroll
    for (int i = 0; i < 2; ++i) {
      int rr0 = (w << 2) + (i << 1);       // 8 waves x 4 rows = 32 keys
      int row = rr0 + (lane >> 5);
      int cs  = lane & 31;
      gload16(vbase + row * DIMC + ((cs ^ (row & 7)) << 3), vsN + (rr0 << 8));
    }
  };
  auto stage_vt = [&](int kt, ushort* vtN) {
    #pragma unroll
    for (int i = 0; i < 2; ++i) {
      int cstart = (w << 7) + (i << 6);    // 1024 chunks of 16B
      int kc = cstart >> 8;                // 0..3 (8 keys each)
      int dim = ((cstart & 255) + lane) ^ (kc << 1);
      gload16(vtb + ((size_t)(bb * DIMC + dim)) * NS + koff + kt * KT + (kc << 3),
              vtN + cstart * 8);
    }
  };

  stage_vs(0, vs0);
  __syncthreads();   // full drain (prologue only)

  f32x4 acc_o[8];      // our 128-d half
  #pragma unroll
  for (int nt = 0; nt < 8; ++nt) { acc_o[nt].x=0.f; acc_o[nt].y=0.f; acc_o[nt].z=0.f; acc_o[nt].w=0.f; }
  float l_s = 0.f;

  ushort* psw = psb + pq * (16 * 40);   // this pq's P^T [16 q][32 k + 8 pad]

  #pragma unroll 1
  for (int t = 0; t < 64; ++t) {
    ushort* vsQ = (t & 1) ? vs1 : vs0;     // QK(t) source (staged t-1)
    ushort* vsS = (t & 1) ? vs0 : vs1;     // stage vs(t+1)
    ushort* vtS = (t & 1) ? vt1 : vt0;     // stage vt(t)   (consumed next phase)
    ushort* vtP = (t & 1) ? vt0 : vt1;     // PV(t-1) source

    if (t + 1 < 64) stage_vs(t + 1, vsS);
    stage_vt(t, vtS);

    // ---- QK^T(t): S^T for our 16-key group
    f32x4 sacc;
    sacc.x=0.f; sacc.y=0.f; sacc.z=0.f; sacc.w=0.f;
    __builtin_amdgcn_s_setprio(1);
    #pragma unroll
    for (int st = 0; st < 8; ++st) {
      const int key = (kh << 4) + l15;
      bf16x8 af = *(const bf16x8*)&vsQ[(key * 32 + ((st * 4 + g) ^ (key & 7))) * 8];
      sacc = __builtin_amdgcn_mfma_f32_16x16x32_bf16(af, qreg[st], sacc, 0, 0, 0);
    }
    __builtin_amdgcn_s_setprio(0);

    // ---- PV(t-1): our 128-d half x full 32 keys (one MFMA per d-tile)
    if (t > 0) {
      bf16x8 pa = *(const bf16x8*)&psw[l15 * 40 + (g << 3)];
      __builtin_amdgcn_s_setprio(1);
      #pragma unroll
      for (int ntl = 0; ntl < 8; ++ntl) {
        const int d = ((kh << 3) + ntl) * 16 + l15;
        bf16x8 vf = *(const bf16x8*)&vtP[((g << 8) + (d ^ (g << 1))) * 8];
        acc_o[ntl] = __builtin_amdgcn_mfma_f32_16x16x32_bf16(vf, pa, acc_o[ntl], 0, 0, 0);
      }
      __builtin_amdgcn_s_setprio(0);
    }

    // ---- softmax(t): P = exp(masked s), l accumulate
    const int ktg6 = (s << 5) + (t >> 1);
    uint mybits = (pmlds[(ktg6 << 1) + (t & 1)] >> ((g << 3) + (kh << 2))) & 0xfu;
    float pv[4];
    #pragma unroll
    for (int r = 0; r < 4; ++r) {
      float vv = (mybits & (1u << r)) ? sacc[r] : -1e30f;
      pv[r] = __expf(vv);
    }
    float rs = (pv[0] + pv[1]) + (pv[2] + pv[3]);
    rs += __shfl_xor(rs, 16);
    rs += __shfl_xor(rs, 32);
    l_s += rs;

    // ---- barrier A: all waves done reading ps(t-1)
    asm volatile("s_waitcnt lgkmcnt(0)" ::: "memory");
    __builtin_amdgcn_sched_barrier(0);
    __builtin_amdgcn_s_barrier();
    __builtin_amdgcn_sched_barrier(0);

    // ---- Pwrite(t): 4 keys (kh*16 + 4g + r) for q=l15
    {
      uint2 pk;
      pk.x = (uint)f2bf(pv[0]) | ((uint)f2bf(pv[1]) << 16);
      pk.y = (uint)f2bf(pv[2]) | ((uint)f2bf(pv[3]) << 16);
      *(uint2*)&psw[l15 * 40 + (kh << 4) + (g << 2)] = pk;
    }

    // ---- barrier B: counted vmcnt (this phase's 4 DMAs stay in flight)
    if (t + 1 < 64)
      asm volatile("s_waitcnt vmcnt(4) lgkmcnt(0)" ::: "memory");
    else
      asm volatile("s_waitcnt vmcnt(2) lgkmcnt(0)" ::: "memory");
    __builtin_amdgcn_sched_barrier(0);
    __builtin_amdgcn_s_barrier();
    __builtin_amdgcn_sched_barrier(0);
  }

  // ---- epilogue: drain vt(63), then PV(63)
  asm volatile("s_waitcnt vmcnt(0)" ::: "memory");
  __builtin_amdgcn_sched_barrier(0);
  __builtin_amdgcn_s_barrier();
  __builtin_amdgcn_sched_barrier(0);
  {
    ushort* vtP = vt1;   // t=63 staged into vt[63&1]=vt1
    bf16x8 pa = *(const bf16x8*)&psw[l15 * 40 + (g << 3)];
    __builtin_amdgcn_s_setprio(1);
    #pragma unroll
    for (int ntl = 0; ntl < 8; ++ntl) {
      const int d = ((kh << 3) + ntl) * 16 + l15;
      bf16x8 vf = *(const bf16x8*)&vtP[((g << 8) + (d ^ (g << 1))) * 8];
      acc_o[ntl] = __builtin_amdgcn_mfma_f32_16x16x32_bf16(vf, pa, acc_o[ntl], 0, 0, 0);
    }
    __builtin_amdgcn_s_setprio(0);
  }

  // ---- write unnormalized partial (our d-half) + per-half l
  {
    const int qrow = qrow_w;
    const size_t obase = (size_t)qrow * DIMC + 4 * g;
    #pragma unroll
    for (int ntl = 0; ntl < 8; ++ntl) {
      f32x4 o = acc_o[ntl];
      *(float4*)&opart[obase + ((kh << 3) + ntl) * 16] = *(float4*)&o;
    }
    if (g == 0) mlp[(size_t)qrow * 2 + kh] = l_s;
  }
}

// ---------------- split-K merge: out = (A + B) / (lA0+lA1+lB0+lB1) ----------
__global__ __launch_bounds__(256) void merge_kernel(
    float* __restrict__ outA, const float* __restrict__ opB,
    const float* __restrict__ mlA, const float* __restrict__ mlB)
{
  int id = blockIdx.x * 256 + threadIdx.x;   // 16384 rows x 64 float4
  int row = id >> 6;
  int c = (id & 63) << 2;
  float lT = (mlA[(size_t)row * 2] + mlA[(size_t)row * 2 + 1]) +
             (mlB[(size_t)row * 2] + mlB[(size_t)row * 2 + 1]);
  float inv = 1.f / lT;
  size_t o = (size_t)row * DIMC + c;
  float4 a = *(const float4*)&outA[o];
  float4 b = *(const float4*)&opB[o];
  float4 r;
  r.x = (a.x + b.x) * inv;
  r.y = (a.y + b.y) * inv;
  r.z = (a.z + b.z) * inv;
  r.w = (a.w + b.w) * inv;
  *(float4*)&outA[o] = r;
}

extern "C" void kernel_launch(void* const* d_in, const int* in_sizes, int n_in,
                              void* d_out, int out_size, void* d_ws, size_t ws_size,
                              hipStream_t stream) {
  const float* x    = (const float*)d_in[0];
  const float* W    = (const float*)d_in[1];
  const float* bias = (const float*)d_in[2];
  const int*   mask = (const int*)d_in[3];
  float* out = (float*)d_out;

  const size_t n = (size_t)NB * NS * DIMC;      // 4.19M elements
  ushort* qb  = (ushort*)d_ws;                  // 8.4 MB
  ushort* vb  = qb + n;                         // 8.4 MB
  ushort* vtb = vb + n;                         // 8.4 MB
  uint* pm32 = (uint*)(vtb + n);                // 2 KB
  ushort* Whl = (ushort*)(pm32 + 512);          // 512 KB
  float* opB = (float*)(Whl + 262144);          // 16.8 MB (s=1 partial)
  float* mlA = opB + n;                         // 128 KB
  float* mlB = mlA + 2 * (NB * NS);             // 128 KB

  prep_kernel<<<514, 256, 0, stream>>>(W, mask, Whl, pm32);
  qv_proj_kernel<<<(NB * NS) / 64, 256, 0, stream>>>(x, Whl, bias, qb, vb, vtb);

  const int smem_bytes = 1024 + 4 * (KT * DIMC) * 2 + 4 * 16 * 40 * 2;  // 70.7 KB
  attn_kernel<<<512, 512, smem_bytes, stream>>>(qb, vb, vtb, pm32, out, opB, mlA, mlB);
  merge_kernel<<<(NB * NS * DIMC / 4) / 256, 256, 0, stream>>>(out, opB, mlA, mlB);
}